// Round 3
// baseline (359.888 us; speedup 1.0000x reference)
//
#include <hip/hip_runtime.h>
#include <stdint.h>

#define BB 4
#define NN 8192
#define MM 2048
#define CC 64
#define OPC 64
#define OUTC 256
#define K0 32
#define K1 64
#define CPW 4    // centers per wave: 512 blocks x 4 waves x 4 = 8192 = B*M

typedef short bf16x8 __attribute__((ext_vector_type(8)));
typedef float f32x4  __attribute__((ext_vector_type(4)));

// fp32 -> bf16 round-to-nearest-even, as raw short (cold path: B fragments only)
__device__ __forceinline__ short f2bf(float f) {
    uint32_t u = __float_as_uint(f);
    u += 0x7FFFu + ((u >> 16) & 1u);
    return (short)(u >> 16);
}

// hot path: HW packed cvt, RNE, 2 floats -> 1 dword (lo = a, hi = b)
__device__ __forceinline__ uint32_t cvt_pk_bf16(float a, float b) {
    uint32_t r;
    asm("v_cvt_pk_bf16_f32 %0, %1, %2" : "=v"(r) : "v"(a), "v"(b));
    return r;
}

// two float4 -> one bf16x8 fragment (RNE, packed cvt)
__device__ __forceinline__ bf16x8 pack8(float4 a, float4 b) {
    union { uint4 u; bf16x8 v; } r;
    r.u.x = cvt_pk_bf16(a.x, a.y);
    r.u.y = cvt_pk_bf16(a.z, a.w);
    r.u.z = cvt_pk_bf16(b.x, b.y);
    r.u.w = cvt_pk_bf16(b.z, b.w);
    return r.v;
}

// ballot-scan 8 distance values (one 512-point chunk, value u at index
// base + u*64 + lane) into the two ring index lists.
__device__ __forceinline__ void process8(const float* dv, int base, int lane,
                                         unsigned long long lt,
                                         int* s0, int* s1,
                                         int& cnt0, int& cnt1) {
#pragma unroll
    for (int u = 0; u < 8; ++u) {
        float d = dv[u];
        bool p0 = (d >= 1.0f)  && (d < 2.25f);
        bool p1 = (d >= 2.25f) && (d < 9.0f);
        unsigned long long m0 = __ballot(p0);
        unsigned long long m1 = __ballot(p1);
        if (cnt0 < K0) {
            int pos = cnt0 + __popcll(m0 & lt);
            if (p0 && pos < K0) s0[pos] = base + u * 64 + lane;
            cnt0 += __popcll(m0);
        }
        if (cnt1 < K1) {
            int pos = cnt1 + __popcll(m1 & lt);
            if (p1 && pos < K1) s1[pos] = base + u * 64 + lane;
            cnt1 += __popcll(m1);
        }
    }
}

// ---------------------------------------------------------------------------
// Fused persistent kernel, direct-register A-fragments (no A-LDS), with
// cross-center distance prefetch and cooperative block-wide agg.
// 512 blocks x 4 waves; wave gw handles centers gw*CPW .. +CPW-1.
// Per center: ballot-select on the PREFETCHED first 512-distance chunk
// (fallback scan for the ~3e-7 case needing more) -> issue next center's
// chunk+xyz prefetch -> per-MFMA-tile register gather of features
// (v_cvt_pk_bf16_f32) -> 16x16x32 bf16 MFMA -> masked relu/max epilogue
// into block-shared x-LDS. After the loop: __syncthreads, then each thread
// owns ONE of 256 output channels for all 16 block centers, so each Wagg
// row is read once per block (4x less L2 traffic than per-wave agg).
// d_ws untouched. LDS ~9.5 KB/block.
// ---------------------------------------------------------------------------
__global__ __launch_bounds__(256, 2) void op_kernel(
    const float* __restrict__ positions, const float* __restrict__ features,
    const float* __restrict__ centers,   const float* __restrict__ distances,
    const float* __restrict__ W0, const float* __restrict__ b0,
    const float* __restrict__ W1, const float* __restrict__ b1,
    const float* __restrict__ Wagg, const float* __restrict__ bagg,
    float* __restrict__ out)
{
    __shared__ float s_x[4][CPW][128];                  // 8 KB, block-shared
    __shared__ int s_idx0[4][K0];
    __shared__ int s_idx1[4][K1];

    const int w    = threadIdx.x >> 6;
    const int lane = threadIdx.x & 63;
    const int quad = lane >> 4;
    const int l15  = lane & 15;
    const int gw   = blockIdx.x * 4 + w;

    // ---- one-time: B fragments for both rings (MFMA B-layout:
    //      lane holds B[k = quad*8+j][n = nt*16 + l15]) ----
    bf16x8 bfr0[3][4], bfr1[3][4];
#pragma unroll
    for (int kc = 0; kc < 3; ++kc) {
#pragma unroll
        for (int nt = 0; nt < 4; ++nt) {
            const int n = nt * 16 + l15;
            bf16x8 v0, v1;
#pragma unroll
            for (int j = 0; j < 8; ++j) {
                int k = kc * 32 + quad * 8 + j;   // permuted k
                float a0 = 0.f, a1 = 0.f;
                if (k < 64)      { a0 = W0[(3 + k) * OPC + n];  a1 = W1[(3 + k) * OPC + n]; }
                else if (k < 67) { a0 = W0[(k - 64) * OPC + n]; a1 = W1[(k - 64) * OPC + n]; }
                v0[j] = f2bf(a0); v1[j] = f2bf(a1);
            }
            bfr0[kc][nt] = v0; bfr1[kc][nt] = v1;
        }
    }
    float bias0v[4], bias1v[4];
#pragma unroll
    for (int nt = 0; nt < 4; ++nt) {
        bias0v[nt] = b0[nt * 16 + l15];
        bias1v[nt] = b1[nt * 16 + l15];
    }
    const unsigned long long lt = (1ull << lane) - 1ull;
    const bf16x8 zf = {0, 0, 0, 0, 0, 0, 0, 0};

    // ---- prologue prefetch: first distance chunk + xyz for center 0 ----
    float dvp[8];
    float cxp, cyp, czp;
    {
        const float* drow0 = distances + (size_t)(gw * CPW) * NN;
#pragma unroll
        for (int u = 0; u < 8; ++u) dvp[u] = drow0[u * 64 + lane];
        cxp = centers[(size_t)(gw * CPW) * 3 + 0];
        cyp = centers[(size_t)(gw * CPW) * 3 + 1];
        czp = centers[(size_t)(gw * CPW) * 3 + 2];
    }

    for (int i = 0; i < CPW; ++i) {
        const int bm = gw * CPW + i;          // < 8192 by construction
        const int b  = bm >> 11;              // MM = 2048
        const float cx = cxp, cy = cyp, cz = czp;

        // ---------------- selection: prefetched chunk 0 + rare fallback ----
        int cnt0 = 0, cnt1 = 0;
        process8(dvp, 0, lane, lt, s_idx0[w], s_idx1[w], cnt0, cnt1);
        if (cnt0 < K0 || cnt1 < K1) {
            const float* drow = distances + (size_t)bm * NN;
            for (int base = 512; base < NN; base += 512) {
                if (cnt0 >= K0 && cnt1 >= K1) break;
                float dv[8];
#pragma unroll
                for (int u = 0; u < 8; ++u) dv[u] = drow[base + u * 64 + lane];
                process8(dv, base, lane, lt, s_idx0[w], s_idx1[w], cnt0, cnt1);
            }
        }
        cnt0 = min(cnt0, K0);
        cnt1 = min(cnt1, K1);

        // ---------------- prefetch next center (hides under GEMMs) ---------
        if (i + 1 < CPW) {
            const float* drn = distances + (size_t)(bm + 1) * NN;
#pragma unroll
            for (int u = 0; u < 8; ++u) dvp[u] = drn[u * 64 + lane];
            cxp = centers[(size_t)(bm + 1) * 3 + 0];
            cyp = centers[(size_t)(bm + 1) * 3 + 1];
            czp = centers[(size_t)(bm + 1) * 3 + 2];
        }

        // ---------------- ring1 GEMM + epilogue ----------------------------
        {
            float cm[4] = {0.f, 0.f, 0.f, 0.f};
#pragma unroll
            for (int mt = 0; mt < 4; ++mt) {
                const int r = mt * 16 + l15;
                const int n = (r < cnt1) ? s_idx1[w][r] : 0;
                const float4* fb = (const float4*)(features + (size_t)((size_t)b * NN + n) * CC);
                float4 a0 = fb[quad * 2],     a1 = fb[quad * 2 + 1];
                float4 a2 = fb[8 + quad * 2], a3 = fb[8 + quad * 2 + 1];
                const float* pp = positions + (size_t)((size_t)b * NN + n) * 3;
                float rx = pp[0] - cx, ry = pp[1] - cy, rz = pp[2] - cz;
                bf16x8 af0 = pack8(a0, a1);
                bf16x8 af1 = pack8(a2, a3);
                union { uint4 u; bf16x8 v; } r2;
                r2.u.x = cvt_pk_bf16(rx, ry);
                r2.u.y = cvt_pk_bf16(rz, 0.0f);
                r2.u.z = 0u; r2.u.w = 0u;
                bf16x8 af2 = (quad == 0) ? r2.v : zf;

                f32x4 acc[4];
#pragma unroll
                for (int nt = 0; nt < 4; ++nt)
                    acc[nt] = (f32x4){bias1v[nt], bias1v[nt], bias1v[nt], bias1v[nt]};
#pragma unroll
                for (int nt = 0; nt < 4; ++nt)
                    acc[nt] = __builtin_amdgcn_mfma_f32_16x16x32_bf16(af0, bfr1[0][nt], acc[nt], 0, 0, 0);
#pragma unroll
                for (int nt = 0; nt < 4; ++nt)
                    acc[nt] = __builtin_amdgcn_mfma_f32_16x16x32_bf16(af1, bfr1[1][nt], acc[nt], 0, 0, 0);
#pragma unroll
                for (int nt = 0; nt < 4; ++nt)
                    acc[nt] = __builtin_amdgcn_mfma_f32_16x16x32_bf16(af2, bfr1[2][nt], acc[nt], 0, 0, 0);
#pragma unroll
                for (int nt = 0; nt < 4; ++nt)
#pragma unroll
                    for (int rr = 0; rr < 4; ++rr) {
                        int m = mt * 16 + quad * 4 + rr;    // C/D: row=quad*4+rr
                        float v = (m < cnt1) ? fmaxf(acc[nt][rr], 0.f) : 0.f;
                        cm[nt] = fmaxf(cm[nt], v);
                    }
            }
#pragma unroll
            for (int nt = 0; nt < 4; ++nt) {
                cm[nt] = fmaxf(cm[nt], __shfl_xor(cm[nt], 16, 64));
                cm[nt] = fmaxf(cm[nt], __shfl_xor(cm[nt], 32, 64));
            }
            float f = (quad == 0) ? cm[0] : (quad == 1) ? cm[1]
                    : (quad == 2) ? cm[2] : cm[3];
            s_x[w][i][64 + lane] = f;     // channel = quad*16+l15 = lane
        }

        // ---------------- ring0 GEMM + epilogue ----------------------------
        {
            float cm[4] = {0.f, 0.f, 0.f, 0.f};
#pragma unroll
            for (int mt = 0; mt < 2; ++mt) {
                const int r = mt * 16 + l15;
                const int n = (r < cnt0) ? s_idx0[w][r] : 0;
                const float4* fb = (const float4*)(features + (size_t)((size_t)b * NN + n) * CC);
                float4 a0 = fb[quad * 2],     a1 = fb[quad * 2 + 1];
                float4 a2 = fb[8 + quad * 2], a3 = fb[8 + quad * 2 + 1];
                const float* pp = positions + (size_t)((size_t)b * NN + n) * 3;
                float rx = pp[0] - cx, ry = pp[1] - cy, rz = pp[2] - cz;
                bf16x8 af0 = pack8(a0, a1);
                bf16x8 af1 = pack8(a2, a3);
                union { uint4 u; bf16x8 v; } r2;
                r2.u.x = cvt_pk_bf16(rx, ry);
                r2.u.y = cvt_pk_bf16(rz, 0.0f);
                r2.u.z = 0u; r2.u.w = 0u;
                bf16x8 af2 = (quad == 0) ? r2.v : zf;

                f32x4 acc[4];
#pragma unroll
                for (int nt = 0; nt < 4; ++nt)
                    acc[nt] = (f32x4){bias0v[nt], bias0v[nt], bias0v[nt], bias0v[nt]};
#pragma unroll
                for (int nt = 0; nt < 4; ++nt)
                    acc[nt] = __builtin_amdgcn_mfma_f32_16x16x32_bf16(af0, bfr0[0][nt], acc[nt], 0, 0, 0);
#pragma unroll
                for (int nt = 0; nt < 4; ++nt)
                    acc[nt] = __builtin_amdgcn_mfma_f32_16x16x32_bf16(af1, bfr0[1][nt], acc[nt], 0, 0, 0);
#pragma unroll
                for (int nt = 0; nt < 4; ++nt)
                    acc[nt] = __builtin_amdgcn_mfma_f32_16x16x32_bf16(af2, bfr0[2][nt], acc[nt], 0, 0, 0);
#pragma unroll
                for (int nt = 0; nt < 4; ++nt)
#pragma unroll
                    for (int rr = 0; rr < 4; ++rr) {
                        int m = mt * 16 + quad * 4 + rr;
                        float v = (m < cnt0) ? fmaxf(acc[nt][rr], 0.f) : 0.f;
                        cm[nt] = fmaxf(cm[nt], v);
                    }
            }
#pragma unroll
            for (int nt = 0; nt < 4; ++nt) {
                cm[nt] = fmaxf(cm[nt], __shfl_xor(cm[nt], 16, 64));
                cm[nt] = fmaxf(cm[nt], __shfl_xor(cm[nt], 32, 64));
            }
            float f = (quad == 0) ? cm[0] : (quad == 1) ? cm[1]
                    : (quad == 2) ? cm[2] : cm[3];
            s_x[w][i][lane] = f;
        }
    }

    // ---------------- cooperative agg conv (block-wide, fp32 VALU) ----------
    // Thread j owns output channel j for all 16 block centers: each Wagg row
    // is read ONCE per block (coalesced 1 KB), s_x reads are LDS broadcasts.
    // Per-output accumulation order over c is identical to the previous
    // per-wave agg -> bitwise-identical results.
    __syncthreads();
    {
        const int j   = threadIdx.x;            // 0..255 = output channel
        const int bm0 = blockIdx.x * 16;        // block's first center
        float acc[16];
        const float bj = bagg[j];
#pragma unroll
        for (int ci = 0; ci < 16; ++ci) acc[ci] = bj;

        for (int c4 = 0; c4 < 32; ++c4) {
            float4 xq[16];
#pragma unroll
            for (int ci = 0; ci < 16; ++ci)
                xq[ci] = *(const float4*)&s_x[ci >> 2][ci & 3][c4 * 4];
            const float wv0 = Wagg[(size_t)(c4 * 4 + 0) * OUTC + j];
            const float wv1 = Wagg[(size_t)(c4 * 4 + 1) * OUTC + j];
            const float wv2 = Wagg[(size_t)(c4 * 4 + 2) * OUTC + j];
            const float wv3 = Wagg[(size_t)(c4 * 4 + 3) * OUTC + j];
#pragma unroll
            for (int ci = 0; ci < 16; ++ci) {
                acc[ci] = fmaf(xq[ci].x, wv0, acc[ci]);
                acc[ci] = fmaf(xq[ci].y, wv1, acc[ci]);
                acc[ci] = fmaf(xq[ci].z, wv2, acc[ci]);
                acc[ci] = fmaf(xq[ci].w, wv3, acc[ci]);
            }
        }
#pragma unroll
        for (int ci = 0; ci < 16; ++ci)
            out[(size_t)(bm0 + ci) * OUTC + j] = fmaxf(acc[ci], 0.f);
    }
}

extern "C" void kernel_launch(void* const* d_in, const int* in_sizes, int n_in,
                              void* d_out, int out_size, void* d_ws, size_t ws_size,
                              hipStream_t stream) {
    const float* positions = (const float*)d_in[0];
    const float* features  = (const float*)d_in[1];
    const float* centers   = (const float*)d_in[2];
    const float* distances = (const float*)d_in[3];
    const float* W0        = (const float*)d_in[4];
    const float* b0        = (const float*)d_in[5];
    const float* W1        = (const float*)d_in[6];
    const float* b1        = (const float*)d_in[7];
    const float* Wagg      = (const float*)d_in[8];
    const float* bagg      = (const float*)d_in[9];
    float* out = (float*)d_out;
    (void)d_ws; (void)ws_size;   // workspace intentionally untouched

    // 512 blocks x 4 waves x CPW(4) centers = 8192 = B*M exactly.
    op_kernel<<<512, 256, 0, stream>>>(positions, features, centers, distances,
                                       W0, b0, W1, b1, Wagg, bagg, out);
}

// Round 5
// 354.318 us; speedup vs baseline: 1.0157x; 1.0157x over previous
//
#include <hip/hip_runtime.h>
#include <stdint.h>

#define BB 4
#define NN 8192
#define MM 2048
#define CC 64
#define OPC 64
#define OUTC 256
#define K0 32
#define K1 64
#define CPW 4    // centers per wave: 512 blocks x 4 waves x 4 = 8192 = B*M
#define XPAD 132 // s_x row stride (pad 128->132: quad-strided agg reads 2-way, free)

typedef short bf16x8 __attribute__((ext_vector_type(8)));
typedef float f32x4  __attribute__((ext_vector_type(4)));

// fp32 -> bf16 round-to-nearest-even, as raw short (cold path: B fragments only)
__device__ __forceinline__ short f2bf(float f) {
    uint32_t u = __float_as_uint(f);
    u += 0x7FFFu + ((u >> 16) & 1u);
    return (short)(u >> 16);
}

// hot path: HW packed cvt, RNE, 2 floats -> 1 dword (lo = a, hi = b)
__device__ __forceinline__ uint32_t cvt_pk_bf16(float a, float b) {
    uint32_t r;
    asm("v_cvt_pk_bf16_f32 %0, %1, %2" : "=v"(r) : "v"(a), "v"(b));
    return r;
}

// two float4 -> one bf16x8 fragment (RNE, packed cvt)
__device__ __forceinline__ bf16x8 pack8(float4 a, float4 b) {
    union { uint4 u; bf16x8 v; } r;
    r.u.x = cvt_pk_bf16(a.x, a.y);
    r.u.y = cvt_pk_bf16(a.z, a.w);
    r.u.z = cvt_pk_bf16(b.x, b.y);
    r.u.w = cvt_pk_bf16(b.z, b.w);
    return r.v;
}

// ballot-scan 8 distance values (one 512-point chunk, value u at index
// base + u*64 + lane) into the two ring index lists.
__device__ __forceinline__ void process8(const float* dv, int base, int lane,
                                         unsigned long long lt,
                                         int* s0, int* s1,
                                         int& cnt0, int& cnt1) {
#pragma unroll
    for (int u = 0; u < 8; ++u) {
        float d = dv[u];
        bool p0 = (d >= 1.0f)  && (d < 2.25f);
        bool p1 = (d >= 2.25f) && (d < 9.0f);
        unsigned long long m0 = __ballot(p0);
        unsigned long long m1 = __ballot(p1);
        if (cnt0 < K0) {
            int pos = cnt0 + __popcll(m0 & lt);
            if (p0 && pos < K0) s0[pos] = base + u * 64 + lane;
            cnt0 += __popcll(m0);
        }
        if (cnt1 < K1) {
            int pos = cnt1 + __popcll(m1 & lt);
            if (p1 && pos < K1) s1[pos] = base + u * 64 + lane;
            cnt1 += __popcll(m1);
        }
    }
}

// ---------------------------------------------------------------------------
// Fused persistent kernel, direct-register A-fragments (no A-LDS), with
// cross-center distance prefetch and REGISTER-LIGHT cooperative agg.
// R3 post-mortem: the previous coop agg's float4 xq[16] (64 VGPR) pushed the
// kernel past 256 VGPR -> 1 block/CU -> lost TLP in the latency-bound gather
// phase. This version: wave w owns output channels [w*64, w*64+64) for all
// 16 block centers; lane owns 4 channels (f32x4 acc[4]) x 4 centers (quad).
// Wagg read once per block (4x less L2 traffic than per-wave agg); peak agg
// live-set ~48 VGPR transient. Accumulation order over c identical to R2.
// d_ws untouched. LDS ~9.9 KB/block.
// (R4 bench was an MI355X container/infra failure, not a kernel fault —
//  resubmitting unchanged to obtain the discriminating measurement.)
// ---------------------------------------------------------------------------
__global__ __launch_bounds__(256, 2) void op_kernel(
    const float* __restrict__ positions, const float* __restrict__ features,
    const float* __restrict__ centers,   const float* __restrict__ distances,
    const float* __restrict__ W0, const float* __restrict__ b0,
    const float* __restrict__ W1, const float* __restrict__ b1,
    const float* __restrict__ Wagg, const float* __restrict__ bagg,
    float* __restrict__ out)
{
    __shared__ float s_x[4][CPW][XPAD];                 // ~8.25 KB, block-shared
    __shared__ int s_idx0[4][K0];
    __shared__ int s_idx1[4][K1];

    const int w    = threadIdx.x >> 6;
    const int lane = threadIdx.x & 63;
    const int quad = lane >> 4;
    const int l15  = lane & 15;
    const int gw   = blockIdx.x * 4 + w;

    // ---- one-time: B fragments for both rings (MFMA B-layout:
    //      lane holds B[k = quad*8+j][n = nt*16 + l15]) ----
    bf16x8 bfr0[3][4], bfr1[3][4];
#pragma unroll
    for (int kc = 0; kc < 3; ++kc) {
#pragma unroll
        for (int nt = 0; nt < 4; ++nt) {
            const int n = nt * 16 + l15;
            bf16x8 v0, v1;
#pragma unroll
            for (int j = 0; j < 8; ++j) {
                int k = kc * 32 + quad * 8 + j;   // permuted k
                float a0 = 0.f, a1 = 0.f;
                if (k < 64)      { a0 = W0[(3 + k) * OPC + n];  a1 = W1[(3 + k) * OPC + n]; }
                else if (k < 67) { a0 = W0[(k - 64) * OPC + n]; a1 = W1[(k - 64) * OPC + n]; }
                v0[j] = f2bf(a0); v1[j] = f2bf(a1);
            }
            bfr0[kc][nt] = v0; bfr1[kc][nt] = v1;
        }
    }
    float bias0v[4], bias1v[4];
#pragma unroll
    for (int nt = 0; nt < 4; ++nt) {
        bias0v[nt] = b0[nt * 16 + l15];
        bias1v[nt] = b1[nt * 16 + l15];
    }
    const unsigned long long lt = (1ull << lane) - 1ull;
    const bf16x8 zf = {0, 0, 0, 0, 0, 0, 0, 0};

    // ---- prologue prefetch: first distance chunk + xyz for center 0 ----
    float dvp[8];
    float cxp, cyp, czp;
    {
        const float* drow0 = distances + (size_t)(gw * CPW) * NN;
#pragma unroll
        for (int u = 0; u < 8; ++u) dvp[u] = drow0[u * 64 + lane];
        cxp = centers[(size_t)(gw * CPW) * 3 + 0];
        cyp = centers[(size_t)(gw * CPW) * 3 + 1];
        czp = centers[(size_t)(gw * CPW) * 3 + 2];
    }

    for (int i = 0; i < CPW; ++i) {
        const int bm = gw * CPW + i;          // < 8192 by construction
        const int b  = bm >> 11;              // MM = 2048
        const float cx = cxp, cy = cyp, cz = czp;

        // ---------------- selection: prefetched chunk 0 + rare fallback ----
        int cnt0 = 0, cnt1 = 0;
        process8(dvp, 0, lane, lt, s_idx0[w], s_idx1[w], cnt0, cnt1);
        if (cnt0 < K0 || cnt1 < K1) {
            const float* drow = distances + (size_t)bm * NN;
            for (int base = 512; base < NN; base += 512) {
                if (cnt0 >= K0 && cnt1 >= K1) break;
                float dv[8];
#pragma unroll
                for (int u = 0; u < 8; ++u) dv[u] = drow[base + u * 64 + lane];
                process8(dv, base, lane, lt, s_idx0[w], s_idx1[w], cnt0, cnt1);
            }
        }
        cnt0 = min(cnt0, K0);
        cnt1 = min(cnt1, K1);

        // ---------------- prefetch next center (hides under GEMMs) ---------
        if (i + 1 < CPW) {
            const float* drn = distances + (size_t)(bm + 1) * NN;
#pragma unroll
            for (int u = 0; u < 8; ++u) dvp[u] = drn[u * 64 + lane];
            cxp = centers[(size_t)(bm + 1) * 3 + 0];
            cyp = centers[(size_t)(bm + 1) * 3 + 1];
            czp = centers[(size_t)(bm + 1) * 3 + 2];
        }

        // ---------------- ring1 GEMM + epilogue ----------------------------
        {
            float cm[4] = {0.f, 0.f, 0.f, 0.f};
#pragma unroll
            for (int mt = 0; mt < 4; ++mt) {
                const int r = mt * 16 + l15;
                const int n = (r < cnt1) ? s_idx1[w][r] : 0;
                const float4* fb = (const float4*)(features + (size_t)((size_t)b * NN + n) * CC);
                float4 a0 = fb[quad * 2],     a1 = fb[quad * 2 + 1];
                float4 a2 = fb[8 + quad * 2], a3 = fb[8 + quad * 2 + 1];
                const float* pp = positions + (size_t)((size_t)b * NN + n) * 3;
                float rx = pp[0] - cx, ry = pp[1] - cy, rz = pp[2] - cz;
                bf16x8 af0 = pack8(a0, a1);
                bf16x8 af1 = pack8(a2, a3);
                union { uint4 u; bf16x8 v; } r2;
                r2.u.x = cvt_pk_bf16(rx, ry);
                r2.u.y = cvt_pk_bf16(rz, 0.0f);
                r2.u.z = 0u; r2.u.w = 0u;
                bf16x8 af2 = (quad == 0) ? r2.v : zf;

                f32x4 acc[4];
#pragma unroll
                for (int nt = 0; nt < 4; ++nt)
                    acc[nt] = (f32x4){bias1v[nt], bias1v[nt], bias1v[nt], bias1v[nt]};
#pragma unroll
                for (int nt = 0; nt < 4; ++nt)
                    acc[nt] = __builtin_amdgcn_mfma_f32_16x16x32_bf16(af0, bfr1[0][nt], acc[nt], 0, 0, 0);
#pragma unroll
                for (int nt = 0; nt < 4; ++nt)
                    acc[nt] = __builtin_amdgcn_mfma_f32_16x16x32_bf16(af1, bfr1[1][nt], acc[nt], 0, 0, 0);
#pragma unroll
                for (int nt = 0; nt < 4; ++nt)
                    acc[nt] = __builtin_amdgcn_mfma_f32_16x16x32_bf16(af2, bfr1[2][nt], acc[nt], 0, 0, 0);
#pragma unroll
                for (int nt = 0; nt < 4; ++nt)
#pragma unroll
                    for (int rr = 0; rr < 4; ++rr) {
                        int m = mt * 16 + quad * 4 + rr;    // C/D: row=quad*4+rr
                        float v = (m < cnt1) ? fmaxf(acc[nt][rr], 0.f) : 0.f;
                        cm[nt] = fmaxf(cm[nt], v);
                    }
            }
#pragma unroll
            for (int nt = 0; nt < 4; ++nt) {
                cm[nt] = fmaxf(cm[nt], __shfl_xor(cm[nt], 16, 64));
                cm[nt] = fmaxf(cm[nt], __shfl_xor(cm[nt], 32, 64));
            }
            float f = (quad == 0) ? cm[0] : (quad == 1) ? cm[1]
                    : (quad == 2) ? cm[2] : cm[3];
            s_x[w][i][64 + lane] = f;     // channel = quad*16+l15 = lane
        }

        // ---------------- ring0 GEMM + epilogue ----------------------------
        {
            float cm[4] = {0.f, 0.f, 0.f, 0.f};
#pragma unroll
            for (int mt = 0; mt < 2; ++mt) {
                const int r = mt * 16 + l15;
                const int n = (r < cnt0) ? s_idx0[w][r] : 0;
                const float4* fb = (const float4*)(features + (size_t)((size_t)b * NN + n) * CC);
                float4 a0 = fb[quad * 2],     a1 = fb[quad * 2 + 1];
                float4 a2 = fb[8 + quad * 2], a3 = fb[8 + quad * 2 + 1];
                const float* pp = positions + (size_t)((size_t)b * NN + n) * 3;
                float rx = pp[0] - cx, ry = pp[1] - cy, rz = pp[2] - cz;
                bf16x8 af0 = pack8(a0, a1);
                bf16x8 af1 = pack8(a2, a3);
                union { uint4 u; bf16x8 v; } r2;
                r2.u.x = cvt_pk_bf16(rx, ry);
                r2.u.y = cvt_pk_bf16(rz, 0.0f);
                r2.u.z = 0u; r2.u.w = 0u;
                bf16x8 af2 = (quad == 0) ? r2.v : zf;

                f32x4 acc[4];
#pragma unroll
                for (int nt = 0; nt < 4; ++nt)
                    acc[nt] = (f32x4){bias0v[nt], bias0v[nt], bias0v[nt], bias0v[nt]};
#pragma unroll
                for (int nt = 0; nt < 4; ++nt)
                    acc[nt] = __builtin_amdgcn_mfma_f32_16x16x32_bf16(af0, bfr0[0][nt], acc[nt], 0, 0, 0);
#pragma unroll
                for (int nt = 0; nt < 4; ++nt)
                    acc[nt] = __builtin_amdgcn_mfma_f32_16x16x32_bf16(af1, bfr0[1][nt], acc[nt], 0, 0, 0);
#pragma unroll
                for (int nt = 0; nt < 4; ++nt)
                    acc[nt] = __builtin_amdgcn_mfma_f32_16x16x32_bf16(af2, bfr0[2][nt], acc[nt], 0, 0, 0);
#pragma unroll
                for (int nt = 0; nt < 4; ++nt)
#pragma unroll
                    for (int rr = 0; rr < 4; ++rr) {
                        int m = mt * 16 + quad * 4 + rr;
                        float v = (m < cnt0) ? fmaxf(acc[nt][rr], 0.f) : 0.f;
                        cm[nt] = fmaxf(cm[nt], v);
                    }
            }
#pragma unroll
            for (int nt = 0; nt < 4; ++nt) {
                cm[nt] = fmaxf(cm[nt], __shfl_xor(cm[nt], 16, 64));
                cm[nt] = fmaxf(cm[nt], __shfl_xor(cm[nt], 32, 64));
            }
            float f = (quad == 0) ? cm[0] : (quad == 1) ? cm[1]
                    : (quad == 2) ? cm[2] : cm[3];
            s_x[w][i][lane] = f;
        }
    }

    // ---------------- cooperative agg conv (wave-split, register-light) ----
    // Wave w owns output channels [w*64, w*64+64) for ALL 16 block centers:
    // Wagg is read once per block (each wave a distinct 64-ch slice).
    // Lane owns channels j4..j4+3 (f32x4 acc) for the 4 centers of its quad
    // group g: center block-local index ci = g*4 + t  ->  s_x[g][t].
    // Accumulation order over c (ascending, u inner) identical to R2.
    __syncthreads();
    {
        const int g   = quad;                    // center subgroup 0..3
        const int j4  = w * 64 + l15 * 4;        // first owned channel
        const int bm0 = blockIdx.x * 16;         // block's first center

        float4 bias4 = *(const float4*)(bagg + j4);
        f32x4 acc[4];
#pragma unroll
        for (int t = 0; t < 4; ++t)
            acc[t] = (f32x4){bias4.x, bias4.y, bias4.z, bias4.w};

#pragma unroll 2
        for (int c4 = 0; c4 < 32; ++c4) {
            float4 xq[4];
#pragma unroll
            for (int t = 0; t < 4; ++t)
                xq[t] = *(const float4*)&s_x[g][t][c4 * 4];
            float4 wv[4];
#pragma unroll
            for (int u = 0; u < 4; ++u)
                wv[u] = *(const float4*)(Wagg + (size_t)(c4 * 4 + u) * OUTC + j4);
#pragma unroll
            for (int u = 0; u < 4; ++u) {
#pragma unroll
                for (int t = 0; t < 4; ++t) {
                    const float xc = (u == 0) ? xq[t].x : (u == 1) ? xq[t].y
                                   : (u == 2) ? xq[t].z : xq[t].w;
                    acc[t][0] = fmaf(xc, wv[u].x, acc[t][0]);
                    acc[t][1] = fmaf(xc, wv[u].y, acc[t][1]);
                    acc[t][2] = fmaf(xc, wv[u].z, acc[t][2]);
                    acc[t][3] = fmaf(xc, wv[u].w, acc[t][3]);
                }
            }
        }
#pragma unroll
        for (int t = 0; t < 4; ++t) {
            float4 o = make_float4(fmaxf(acc[t][0], 0.f), fmaxf(acc[t][1], 0.f),
                                   fmaxf(acc[t][2], 0.f), fmaxf(acc[t][3], 0.f));
            *(float4*)(out + (size_t)(bm0 + g * 4 + t) * OUTC + j4) = o;
        }
    }
}

extern "C" void kernel_launch(void* const* d_in, const int* in_sizes, int n_in,
                              void* d_out, int out_size, void* d_ws, size_t ws_size,
                              hipStream_t stream) {
    const float* positions = (const float*)d_in[0];
    const float* features  = (const float*)d_in[1];
    const float* centers   = (const float*)d_in[2];
    const float* distances = (const float*)d_in[3];
    const float* W0        = (const float*)d_in[4];
    const float* b0        = (const float*)d_in[5];
    const float* W1        = (const float*)d_in[6];
    const float* b1        = (const float*)d_in[7];
    const float* Wagg      = (const float*)d_in[8];
    const float* bagg      = (const float*)d_in[9];
    float* out = (float*)d_out;
    (void)d_ws; (void)ws_size;   // workspace intentionally untouched

    // 512 blocks x 4 waves x CPW(4) centers = 8192 = B*M exactly.
    op_kernel<<<512, 256, 0, stream>>>(positions, features, centers, distances,
                                       W0, b0, W1, b1, Wagg, bagg, out);
}